// Round 2
// 272.726 us; speedup vs baseline: 1.0278x; 1.0278x over previous
//
#include <hip/hip_runtime.h>

#define NODE_DIM 8

typedef __attribute__((ext_vector_type(8))) short short8;
typedef __attribute__((ext_vector_type(4))) float f32x4;

// 8-term dot; param must not be named w/x/y/z (macro hits member access).
#define DOT8(xv, WT) ((xv)[0]*(WT)[0] + (xv)[1]*(WT)[1] + (xv)[2]*(WT)[2] + (xv)[3]*(WT)[3] + \
                      (xv)[4]*(WT)[4] + (xv)[5]*(WT)[5] + (xv)[6]*(WT)[6] + (xv)[7]*(WT)[7])

// Single-instruction RNE fp32 pair -> packed bf16x2 (a -> low16, b -> high16).
static __device__ __forceinline__ unsigned cvt_pk_bf16(float a, float b) {
    unsigned r;
    asm("v_cvt_pk_bf16_f32 %0, %1, %2" : "=v"(r) : "v"(a), "v"(b));
    return r;
}

// ---------------------------------------------------------------------------
// Edge kernel R8: same MFMA formulation as R7 ([E,256] @ [256,32] bf16,
// 16 edges/group, K = 9 steps of 32 with step 8 = b2 bias-row extension),
// with two latency fixes:
//   (1) A-frag packing via v_cvt_pk_bf16_f32 (1 instr vs ~9 manual) — cuts
//       the per-group VALU count ~3x (was the bulk of VALUBusy=28%).
//   (2) TWO groups in flight per wave iteration (independent chains: eidx/
//       ea/x loads for both issued up front, B ds_reads shared between the
//       two groups' MFMAs, atomics batched at the end) — doubles per-wave
//       MLP to hide the x-gather and atomic latency that keeps every pipe
//       <30% busy.
//   kk=8 identity A-frag (h=1) precomputed once per group.
// Scatter-mean atomics unchanged (32/edge, coalesced 64B per quad).
// ---------------------------------------------------------------------------
__global__ __launch_bounds__(256, 4)
void edge_kernel(const float* __restrict__ x,
                 const float* __restrict__ ea,
                 const int* __restrict__ eidx,
                 const float* __restrict__ W1, const float* __restrict__ b1,
                 const float* __restrict__ W2, const float* __restrict__ b2,
                 float* __restrict__ s, int* __restrict__ cnt,
                 int E)
{
    __shared__ __align__(16) short lds_b[18 * 64 * 8];

    const int t = threadIdx.x;

    // ---- stage B fragments (bf16, frag-order) once per block ----
    for (int f = t; f < 18 * 64 * 8; f += 256) {
        const int j   = f & 7;
        const int ln  = (f >> 3) & 63;
        const int fid = f >> 9;            // 0..17
        const int kk  = fid >> 1, ot = fid & 1;
        const int qq  = ln >> 4, ol = ln & 15;
        float v;
        if (kk < 8) v = W2[(kk * 4 + qq) * 256 + j * 32 + ot * 16 + ol];
        else        v = (qq == 0) ? b2[j * 32 + ot * 16 + ol] : 0.f;
        unsigned uv = __float_as_uint(v);
        uv = (uv + 0x7fffu + ((uv >> 16) & 1u)) >> 16;
        lds_b[f] = (short)uv;
    }
    __syncthreads();

    const int lane = t & 63;
    const int e_l  = lane & 15;    // edge slot within group (A: m, C: n!)
    const int q    = lane >> 4;    // quad

    // W1 columns for this lane's h set: k = 4t+q.
    float w10[8], w11[8], w12[8], b1r[8];
#pragma unroll
    for (int t2 = 0; t2 < 8; ++t2) {
        const int k = 4 * t2 + q;
        w10[t2] = W1[k]; w11[t2] = W1[32 + k]; w12[t2] = W1[64 + k]; b1r[t2] = b1[k];
    }

    const int wave = blockIdx.x * 4 + (t >> 6);
    const int nwav = gridDim.x * 4;
    const int ngrp = (E + 15) / 16;

    for (int g0 = 2 * wave; g0 < ngrp; g0 += 2 * nwav) {
        const bool v1    = (g0 + 1) < ngrp;
        const int  base0 = g0 * 16;
        const int  base1 = (v1 ? g0 + 1 : g0) * 16;

        int ej0 = base0 + e_l; if (ej0 >= E) ej0 = E - 1;
        int ej1 = base1 + e_l; if (ej1 >= E) ej1 = E - 1;

        // ---- all global loads for both groups issued up front ----
        const int src0 = eidx[ej0];
        const int dst0 = eidx[E + ej0];
        const int src1 = eidx[ej1];
        const int dst1 = eidx[E + ej1];
        const float ea00 = ea[3 * ej0], ea01 = ea[3 * ej0 + 1], ea02 = ea[3 * ej0 + 2];
        const float ea10 = ea[3 * ej1], ea11 = ea[3 * ej1 + 1], ea12 = ea[3 * ej1 + 2];
        const float4 xa0 = *(const float4*)(x + (size_t)(unsigned)src0 * 8);
        const float4 xb0 = *(const float4*)(x + (size_t)(unsigned)src0 * 8 + 4);
        const float4 xa1 = *(const float4*)(x + (size_t)(unsigned)src1 * 8);
        const float4 xb1 = *(const float4*)(x + (size_t)(unsigned)src1 * 8 + 4);
        const float xr0[8] = {xa0.x, xa0.y, xa0.z, xa0.w, xb0.x, xb0.y, xb0.z, xb0.w};
        const float xr1[8] = {xa1.x, xa1.y, xa1.z, xa1.w, xb1.x, xb1.y, xb1.z, xb1.w};

        float h0[8], h1[8];
#pragma unroll
        for (int t2 = 0; t2 < 8; ++t2) {
            const float z0 = b1r[t2] + ea00 * w10[t2] + ea01 * w11[t2] + ea02 * w12[t2];
            const float z1 = b1r[t2] + ea10 * w10[t2] + ea11 * w11[t2] + ea12 * w12[t2];
            h0[t2] = z0 > 0.f ? z0 : 0.f;
            h1[t2] = z1 > 0.f ? z1 : 0.f;
        }

        f32x4 a00 = {0.f, 0.f, 0.f, 0.f};
        f32x4 a01 = {0.f, 0.f, 0.f, 0.f};
        f32x4 a10 = {0.f, 0.f, 0.f, 0.f};
        f32x4 a11 = {0.f, 0.f, 0.f, 0.f};

        // ---- kk=8 bias rows first (A = pk(x), h==1; B zero except q==0) ----
        {
            union { short8 v; unsigned u[4]; } id0, id1;
#pragma unroll
            for (int p = 0; p < 4; ++p) {
                id0.u[p] = cvt_pk_bf16(xr0[2 * p], xr0[2 * p + 1]);
                id1.u[p] = cvt_pk_bf16(xr1[2 * p], xr1[2 * p + 1]);
            }
            const short8 bf0 = *(const short8*)&lds_b[(16 * 64 + lane) * 8];
            const short8 bf1 = *(const short8*)&lds_b[(17 * 64 + lane) * 8];
            a00 = __builtin_amdgcn_mfma_f32_16x16x32_bf16(id0.v, bf0, a00, 0, 0, 0);
            a01 = __builtin_amdgcn_mfma_f32_16x16x32_bf16(id0.v, bf1, a01, 0, 0, 0);
            a10 = __builtin_amdgcn_mfma_f32_16x16x32_bf16(id1.v, bf0, a10, 0, 0, 0);
            a11 = __builtin_amdgcn_mfma_f32_16x16x32_bf16(id1.v, bf1, a11, 0, 0, 0);
        }

        // ---- main K loop: B-frags shared by both groups ----
#pragma unroll
        for (int kk = 0; kk < 8; ++kk) {
            const short8 bf0 = *(const short8*)&lds_b[((kk * 2 + 0) * 64 + lane) * 8];
            const short8 bf1 = *(const short8*)&lds_b[((kk * 2 + 1) * 64 + lane) * 8];
            const float hk0 = h0[kk], hk1 = h1[kk];
            union { short8 v; unsigned u[4]; } af0, af1;
#pragma unroll
            for (int p = 0; p < 4; ++p) {
                af0.u[p] = cvt_pk_bf16(hk0 * xr0[2 * p], hk0 * xr0[2 * p + 1]);
                af1.u[p] = cvt_pk_bf16(hk1 * xr1[2 * p], hk1 * xr1[2 * p + 1]);
            }
            a00 = __builtin_amdgcn_mfma_f32_16x16x32_bf16(af0.v, bf0, a00, 0, 0, 0);
            a01 = __builtin_amdgcn_mfma_f32_16x16x32_bf16(af0.v, bf1, a01, 0, 0, 0);
            a10 = __builtin_amdgcn_mfma_f32_16x16x32_bf16(af1.v, bf0, a10, 0, 0, 0);
            a11 = __builtin_amdgcn_mfma_f32_16x16x32_bf16(af1.v, bf1, a11, 0, 0, 0);
        }

        // ---- scatter: C row m = q*4+r (edge base+m), col = e_l (o_local) ----
#pragma unroll
        for (int r = 0; r < 4; ++r) {
            const int m   = q * 4 + r;
            const int dr0 = __shfl(dst0, m, 16);   // dst held by lane with e_l==m
            const int dr1 = __shfl(dst1, m, 16);
            if (base0 + m < E) {
                atomicAdd(&s[(size_t)(unsigned)dr0 * 32 + e_l],      a00[r]);
                atomicAdd(&s[(size_t)(unsigned)dr0 * 32 + 16 + e_l], a01[r]);
            }
            if (v1 && base1 + m < E) {
                atomicAdd(&s[(size_t)(unsigned)dr1 * 32 + e_l],      a10[r]);
                atomicAdd(&s[(size_t)(unsigned)dr1 * 32 + 16 + e_l], a11[r]);
            }
        }
        if (lane < 16) {
            if (base0 + e_l < E)       atomicAdd(&cnt[dst0], 1);
            if (v1 && base1 + e_l < E) atomicAdd(&cnt[dst1], 1);
        }
    }
}

// ---------------------------------------------------------------------------
// Node transform + partial pool: 256 threads = 8 nodes x 32 dims; blocks whose
// nodes share one graph LDS-reduce to one atomic per (block,o).
// ---------------------------------------------------------------------------
__global__ __launch_bounds__(256)
void node_pool_kernel(const float* __restrict__ s,
                      const int* __restrict__ cnt,
                      const float* __restrict__ x,
                      const float* __restrict__ root,
                      const float* __restrict__ conv_bias,
                      const int* __restrict__ batch,
                      float* __restrict__ gsum, int N)
{
    __shared__ float red[256];
    const int t    = threadIdx.x;
    const int o    = t & 31;
    const int slot = t >> 5;
    const int base = blockIdx.x * 8;
    const int n    = base + slot;

    float rootr[8];
#pragma unroll
    for (int i = 0; i < 8; ++i) rootr[i] = root[i * 32 + o];
    const float cb = conv_bias[o];

    float v = 0.f;
    int   b = 0;
    if (n < N) {
        b = batch[n];
        const int   c    = cnt[n];
        const float rinv = 1.f / (float)(c > 1 ? c : 1);
        const float* xp  = x + (size_t)n * 8;
        float xv[8];
#pragma unroll
        for (int i = 0; i < 8; ++i) xv[i] = xp[i];
        const float t2 = s[(size_t)n * 32 + o] * rinv + cb + DOT8(xv, rootr);
        v = t2 > 0.f ? t2 : 0.f;
    }

    const int nlast  = (base + 7 < N) ? base + 7 : N - 1;
    const int bfirst = batch[base];
    const int blast  = batch[nlast];

    if (bfirst == blast && base + 7 < N) {
        red[t] = v;
        __syncthreads();
        if (t < 32) {
            float p = 0.f;
#pragma unroll
            for (int c2 = 0; c2 < 8; ++c2) p += red[t + 32 * c2];
            atomicAdd(&gsum[bfirst * 32 + t], p);
        }
    } else {
        if (n < N) atomicAdd(&gsum[b * 32 + o], v);
    }
}

// ---------------------------------------------------------------------------
// MLP head: one 128-thread block per graph.
// ---------------------------------------------------------------------------
__global__ __launch_bounds__(128)
void mlp_kernel(const float* __restrict__ gsum,
                const int* __restrict__ batch,
                const float* __restrict__ ratios,
                const int* __restrict__ ids,
                const float* __restrict__ emb,
                const float* __restrict__ fc0w, const float* __restrict__ fc0b,
                const float* __restrict__ fc1w, const float* __restrict__ fc1b,
                const float* __restrict__ fc2w, const float* __restrict__ fc2b,
                float* __restrict__ out, int N)
{
    __shared__ float zs[96];
    __shared__ float z1[64];
    __shared__ float z2[32];
    __shared__ int seg[2];

    const int g = blockIdx.x;
    const int t = threadIdx.x;

    if (t < 2) {
        const int target = g + t;
        int lo = 0, hi = N;
        while (lo < hi) {
            const int mid = (lo + hi) >> 1;
            if (batch[mid] < target) lo = mid + 1; else hi = mid;
        }
        seg[t] = lo;
    }
    __syncthreads();

    float c = (float)(seg[1] - seg[0]);
    if (c < 1.f) c = 1.f;

    if (t < 32) zs[t] = gsum[g * 32 + t] / c;
    if (t >= 32 && t < 96) {
        const int j = t - 32;
        float u = 0.f;
#pragma unroll
        for (int r = 0; r < 5; ++r) u += ratios[r] * emb[(size_t)ids[r] * 64 + j];
        zs[32 + j] = u;
    }
    __syncthreads();

    if (t < 64) {
        float a = fc0b[t];
        for (int k = 0; k < 96; ++k) a += zs[k] * fc0w[k * 64 + t];
        z1[t] = a > 0.f ? a : 0.f;
    }
    __syncthreads();

    if (t < 32) {
        float a = fc1b[t];
        for (int k = 0; k < 64; ++k) a += z1[k] * fc1w[k * 32 + t];
        z2[t] = a > 0.f ? a : 0.f;
    }
    __syncthreads();

    if (t == 0) {
        float a = fc2b[0];
        for (int k = 0; k < 32; ++k) a += z2[k] * fc2w[k];
        out[g] = a;
    }
}

// ---------------------------------------------------------------------------
extern "C" void kernel_launch(void* const* d_in, const int* in_sizes, int n_in,
                              void* d_out, int out_size, void* d_ws, size_t ws_size,
                              hipStream_t stream)
{
    const float* x         = (const float*)d_in[0];
    const float* ea        = (const float*)d_in[1];
    const float* ratios    = (const float*)d_in[2];
    const int*   eidx      = (const int*)  d_in[3];
    const int*   batch     = (const int*)  d_in[4];
    const int*   ids       = (const int*)  d_in[5];
    const float* W1        = (const float*)d_in[6];
    const float* b1        = (const float*)d_in[7];
    const float* W2        = (const float*)d_in[8];
    const float* b2        = (const float*)d_in[9];
    const float* emb       = (const float*)d_in[10];
    const float* root      = (const float*)d_in[11];
    const float* conv_bias = (const float*)d_in[12];
    const float* fc0w      = (const float*)d_in[13];
    const float* fc0b      = (const float*)d_in[14];
    const float* fc1w      = (const float*)d_in[15];
    const float* fc1b      = (const float*)d_in[16];
    const float* fc2w      = (const float*)d_in[17];
    const float* fc2b      = (const float*)d_in[18];

    const int N = in_sizes[0] / NODE_DIM;   // 50000
    const int E = in_sizes[1] / 3;          // 1000000
    const int G = out_size;                 // 128

    float* s    = (float*)d_ws;                                               // [N,32]
    int*   cnt  = (int*)((char*)d_ws + (size_t)N * 32 * 4);                   // [N]
    float* gsum = (float*)((char*)d_ws + (size_t)N * 32 * 4 + (size_t)N * 4); // [G,32]
    (void)hipMemsetAsync(d_ws, 0, (size_t)N * 32 * 4 + (size_t)N * 4 + (size_t)G * 32 * 4, stream);

    edge_kernel<<<2048, 256, 0, stream>>>(x, ea, eidx, W1, b1, W2, b2, s, cnt, E);
    node_pool_kernel<<<(N + 7) / 8, 256, 0, stream>>>(s, cnt, x, root, conv_bias,
                                                      batch, gsum, N);
    mlp_kernel<<<G, 128, 0, stream>>>(gsum, batch, ratios, ids, emb,
                                      fc0w, fc0b, fc1w, fc1b, fc2w, fc2b,
                                      (float*)d_out, N);
}